// Round 5
// baseline (200.456 us; speedup 1.0000x reference)
//
#include <hip/hip_runtime.h>
#include <hip/hip_bf16.h>

// Problem constants
#define BATCH  128
#define HWN    196          // (224/16)^2 patches per sample
#define HIDN   768
#define KN     768          // 3*16*16
#define IMGSZ  224
#define IMG2   (224*224)
#define MTOT   (BATCH*HWN)  // 25088 output rows

// GEMM tiling
#define BM 128
#define BN 128
#define BK 32
#define NITER (KN / BK)     // 24

typedef __attribute__((ext_vector_type(8))) short bf16x8;
typedef __attribute__((ext_vector_type(4))) float floatx4;

#define GP(p) ((const __attribute__((address_space(1))) void*)(p))
#define SP(p) ((__attribute__((address_space(3))) void*)(p))

static __device__ __forceinline__ short f2bf(float f) {
    __hip_bfloat16 h = __float2bfloat16(f);   // RNE
    return __builtin_bit_cast(short, h);
}

static __device__ __forceinline__ bf16x8 cvt2x4(float4 f0, float4 f1) {
    bf16x8 v;
    v[0]=f2bf(f0.x); v[1]=f2bf(f0.y); v[2]=f2bf(f0.z); v[3]=f2bf(f0.w);
    v[4]=f2bf(f1.x); v[5]=f2bf(f1.y); v[6]=f2bf(f1.z); v[7]=f2bf(f1.w);
    return v;
}

// ---------------------------------------------------------------------------
// prep_W: fp32 -> bf16, 768*768 elems, 8 per thread. ~2 us.
// ---------------------------------------------------------------------------
__global__ __launch_bounds__(256)
void prep_W(const float* __restrict__ W, unsigned short* __restrict__ Wb)
{
    const int idx = blockIdx.x * 256 + threadIdx.x;   // < 73728
    const float* src = W + (size_t)idx * 8;
    float4 f0 = *(const float4*)(src);
    float4 f1 = *(const float4*)(src + 4);
    *(bf16x8*)(Wb + (size_t)idx * 8) = cvt2x4(f0, f1);
}

// ---------------------------------------------------------------------------
// Fused gather-GEMM: C[r,n] = sum_k x[b, perm-patch(r), k]*Wb[n,k] + bias[n]
// - A staged straight from x: fp32 loads held in regs one iter, converted to
//   bf16 and ds_written one iter later (barrier drains the loads for free).
// - B staged async via global_load_lds from bf16 Wb.
// - XCD-partitioned 1D tile map (round-4 verified: FETCH 119->31 MB).
// - Transposed-D (swapped mfma operands) -> float4 epilogue stores.
// ---------------------------------------------------------------------------
__global__ __launch_bounds__(256, 4)
void gemm(const float* __restrict__ x, const unsigned short* __restrict__ Wb,
          const float* __restrict__ bias, const int* __restrict__ perm,
          float* __restrict__ out)
{
    __shared__ __align__(16) unsigned short As[2][BM * BK];  // 2 x 8 KB
    __shared__ __align__(16) unsigned short Bs[2][BN * BK];  // 2 x 8 KB

    const int tid = threadIdx.x;

    // ---- XCD-partitioned tile decode: 1176 tiles, 8 bm-groups
    // groups 0..3: 25 bm-tiles (150 tiles), groups 4..7: 24 (144 tiles).
    // XCD k has 147 slots; low groups' overflow (3 tiles) goes to xcd k+4.
    const int L   = blockIdx.x;       // 0..1175
    const int xcd = L & 7;
    const int s   = L >> 3;           // 0..146
    int grp, t;
    if (xcd < 4)        { grp = xcd;     t = s; }
    else if (s < 144)   { grp = xcd;     t = s; }
    else                { grp = xcd - 4; t = 147 + (s - 144); }
    const int bm0 = (grp < 4) ? grp * 25 : 100 + (grp - 4) * 24;
    const int bm  = bm0 + t / 6;      // 0..195
    const int bn  = t % 6;            // bn-fastest: 6 same-A tiles consecutive

    // ---- A staging map: 4 threads per row, 8 k-elems each; 2 rows per thread.
    const int arow_i = tid >> 2;          // 0..63  (rows arow_i and arow_i+64)
    const int kseg   = tid & 3;           // 8-elem k-segment within BK
    const int gr0 = bm * BM + arow_i;
    const int gr1 = gr0 + 64;
    const int p0 = perm[gr0], p1 = perm[gr1];
    const float* arow0 = x + (size_t)(gr0 / HWN) * 3 * IMG2
                           + (size_t)((p0 / 14) * 16) * IMGSZ + (p0 % 14) * 16;
    const float* arow1 = x + (size_t)(gr1 / HWN) * 3 * IMG2
                           + (size_t)((p1 / 14) * 16) * IMGSZ + (p1 % 14) * 16;

    // ---- B staging map (async DMA): row tid>>2, seg tid&3, 2 rows/thread.
    const unsigned short* gb = Wb + (size_t)(bn * BN + (tid >> 2)) * KN + kseg * 8;

    // ---- wave/fragment coords
    const int lane = tid & 63;
    const int wave = tid >> 6;
    const int wm = (wave >> 1) * 64;
    const int wn = (wave & 1) * 64;
    const int lr = lane & 15;
    const int lq = lane >> 4;

    floatx4 acc[4][4] = {};

    // per-iter x offset for this thread's 8 k-values: kk = k0 + kseg*8
    auto xoff = [&](int k0) {
        const int kk = k0 + kseg * 8;
        return (kk >> 8) * IMG2 + (((kk >> 4) & 15) * IMGSZ) + (kk & 15);
    };
    auto issueB = [&](int i, int b) {
        __builtin_amdgcn_global_load_lds(GP(gb + i * BK),           SP(&Bs[b][tid * 8]),        16, 0, 0);
        __builtin_amdgcn_global_load_lds(GP(gb + 64 * KN + i * BK), SP(&Bs[b][2048 + tid * 8]), 16, 0, 0);
    };

    float4 f0, f1, f2, f3;            // A fp32 in flight (tile i+1 during iter i)
    auto loadA = [&](int i) {
        const int off = xoff(i * BK);
        f0 = *(const float4*)(arow0 + off);
        f1 = *(const float4*)(arow0 + off + 4);
        f2 = *(const float4*)(arow1 + off);
        f3 = *(const float4*)(arow1 + off + 4);
    };
    auto writeA = [&](int b) {
        *(bf16x8*)&As[b][tid * 8]        = cvt2x4(f0, f1);
        *(bf16x8*)&As[b][2048 + tid * 8] = cvt2x4(f2, f3);
    };
    auto compute = [&](int b) {
        bf16x8 bfrag[4];
        #pragma unroll
        for (int j = 0; j < 4; ++j)
            bfrag[j] = *(const bf16x8*)&Bs[b][(wn + j * 16 + lr) * BK + lq * 8];
        #pragma unroll
        for (int i = 0; i < 4; ++i) {
            bf16x8 afrag = *(const bf16x8*)&As[b][(wm + i * 16 + lr) * BK + lq * 8];
            #pragma unroll
            for (int j = 0; j < 4; ++j)   // swapped operands -> transposed D
                acc[i][j] = __builtin_amdgcn_mfma_f32_16x16x32_bf16(
                                bfrag[j], afrag, acc[i][j], 0, 0, 0);
        }
    };

    // ---- prologue: tile 0 staged synchronously; tile 1 A-loads in flight
    loadA(0);
    issueB(0, 0);
    writeA(0);          // waits on f-regs (once)
    loadA(1);

    // ---- main loop: one barrier per iter
    for (int i = 0; i < NITER; ++i) {
        __syncthreads();                       // As/Bs[i&1] ready; drains f-regs
        if (i + 1 < NITER) {
            issueB(i + 1, (i + 1) & 1);        // covered by compute(i)
            writeA((i + 1) & 1);               // f-regs from iter i-1, ready
        }
        if (i + 2 < NITER) loadA(i + 2);       // covered by compute(i)
        compute(i & 1);
    }

    // ---- epilogue: transposed C/D -> row = lr, 4 consecutive cols = lq*4+reg
    #pragma unroll
    for (int j = 0; j < 4; ++j) {
        const int gc0 = bn * BN + wn + j * 16 + lq * 4;
        const float4 bv = *(const float4*)&bias[gc0];
        #pragma unroll
        for (int i = 0; i < 4; ++i) {
            const int grow = bm * BM + wm + i * 16 + lr;
            float4 v;
            v.x = acc[i][j][0] + bv.x;
            v.y = acc[i][j][1] + bv.y;
            v.z = acc[i][j][2] + bv.z;
            v.w = acc[i][j][3] + bv.w;
            *(float4*)(out + (size_t)grow * HIDN + gc0) = v;
        }
    }
}

extern "C" void kernel_launch(void* const* d_in, const int* in_sizes, int n_in,
                              void* d_out, int out_size, void* d_ws, size_t ws_size,
                              hipStream_t stream) {
    const float* x    = (const float*)d_in[0];
    const float* W    = (const float*)d_in[1];
    const float* bias = (const float*)d_in[2];
    const int*   perm = (const int*)d_in[3];
    float* out = (float*)d_out;

    // workspace: Wb bf16 [768*768] (1.2 MB)
    unsigned short* Wb = (unsigned short*)d_ws;

    prep_W<<<dim3(KN * HIDN / 8 / 256), dim3(256), 0, stream>>>(W, Wb);
    gemm<<<dim3(1176), dim3(256), 0, stream>>>(x, Wb, bias, perm, out);
}